// Round 1
// 1247.809 us; speedup vs baseline: 1.0529x; 1.0529x over previous
//
#include <hip/hip_runtime.h>

// Problem constants
#define Nn 50000
#define Ee 625000
#define INDIM 128
#define NH 8
#define HDIM 16
// H*D = 128 output cols; K = 128

typedef __attribute__((ext_vector_type(8))) short short8;
typedef __attribute__((ext_vector_type(4))) float floatx4;

__device__ inline unsigned short f2bf(float f) {
    unsigned u = __builtin_bit_cast(unsigned, f);
    u = (u + 0x7FFFu + ((u >> 16) & 1u)) >> 16;  // round-to-nearest-even
    return (unsigned short)u;
}

__device__ inline short8 cvt8(float4 a, float4 b) {
    short8 o;
    o[0] = (short)f2bf(a.x); o[1] = (short)f2bf(a.y);
    o[2] = (short)f2bf(a.z); o[3] = (short)f2bf(a.w);
    o[4] = (short)f2bf(b.x); o[5] = (short)f2bf(b.y);
    o[6] = (short)f2bf(b.z); o[7] = (short)f2bf(b.w);
    return o;
}

// B-fragment: 8 consecutive-k bf16 of W^T[n][k0..k0+8) from f32 W stored [k][128].
// W is 64 KB total, L2-resident across all blocks -> strided scalar loads are cheap.
__device__ inline short8 wfrag(const float* __restrict__ W, int n, int k0) {
    short8 o;
#pragma unroll
    for (int j = 0; j < 8; ++j) o[j] = (short)f2bf(W[(size_t)(k0 + j) * 128 + n]);
    return o;
}

// ---------------- Node projections: Q/K/V = h @ W + b ----------------
// No LDS, no barriers: each wave's A-fragments are its own 32 rows (zero
// cross-wave reuse), loaded direct global->reg. Grid.y = matrix index.
__global__ __launch_bounds__(256, 4) void node_qkv(
    const float* __restrict__ h,
    const float* __restrict__ Wq, const float* __restrict__ bq,
    const float* __restrict__ Wk, const float* __restrict__ bk,
    const float* __restrict__ Wv, const float* __restrict__ bv,
    float* __restrict__ Q, float* __restrict__ K, float* __restrict__ V) {
    int tid = threadIdx.x;
    int wave = tid >> 6, lane = tid & 63;
    int q4 = lane >> 4, col = lane & 15;
    long n0 = (long)blockIdx.x * 128;
    int mat = blockIdx.y;
    const float* W = (mat == 0) ? Wq : (mat == 1) ? Wk : Wv;
    const float* b = (mat == 0) ? bq : (mat == 1) ? bk : bv;
    float*       O = (mat == 0) ? Q  : (mat == 1) ? K  : V;

    // A fragments: lane holds rows n0 + mt*16 + col, k = kc*32 + q4*8 .. +8
    short8 afr[2][4];
#pragma unroll
    for (int t = 0; t < 2; ++t) {
        long row = n0 + (wave * 2 + t) * 16 + col;
        bool v = row < Nn;
        const float* p = h + row * 128 + q4 * 8;
#pragma unroll
        for (int kc = 0; kc < 4; ++kc) {
            float4 x = make_float4(0.f, 0.f, 0.f, 0.f);
            float4 y = make_float4(0.f, 0.f, 0.f, 0.f);
            if (v) {
                x = *reinterpret_cast<const float4*>(p + kc * 32);
                y = *reinterpret_cast<const float4*>(p + kc * 32 + 4);
            }
            afr[t][kc] = cvt8(x, y);
        }
    }

    for (int n = 0; n < 8; ++n) {
        short8 bfr[4];
#pragma unroll
        for (int kc = 0; kc < 4; ++kc) bfr[kc] = wfrag(W, n * 16 + col, kc * 32 + q4 * 8);
        float bias = b[n * 16 + col];
#pragma unroll
        for (int t = 0; t < 2; ++t) {
            floatx4 acc = {0.f, 0.f, 0.f, 0.f};
#pragma unroll
            for (int kc = 0; kc < 4; ++kc)
                acc = __builtin_amdgcn_mfma_f32_16x16x32_bf16(afr[t][kc], bfr[kc], acc, 0, 0, 0);
#pragma unroll
            for (int r = 0; r < 4; ++r) {
                long node = n0 + (wave * 2 + t) * 16 + q4 * 4 + r;
                if (node < Nn) O[node * 128 + n * 16 + col] = acc[r] + bias;
            }
        }
    }
}

// ---------------- Fused edge kernel: pe GEMM + score + e_out + s + atomics ----------------
// Zero LDS, zero barriers -> occupancy capped only by VGPRs (target 4 waves/EU).
__global__ __launch_bounds__(256, 4) void edge_fused(
    const float* __restrict__ e, const int* __restrict__ src, const int* __restrict__ dst,
    const float* __restrict__ We, const float* __restrict__ be,
    const float* __restrict__ Q, const float* __restrict__ K, const float* __restrict__ V,
    float* __restrict__ e_out, float* __restrict__ hacc, float* __restrict__ z) {
    int tid = threadIdx.x;
    int wave = tid >> 6, lane = tid & 63;
    int q4 = lane >> 4, col = lane & 15;
    long e0 = (long)blockIdx.x * 128;

    // A fragments (edge rows), direct global -> bf16 regs
    short8 afr[2][4];
#pragma unroll
    for (int t = 0; t < 2; ++t) {
        long row = e0 + (wave * 2 + t) * 16 + col;
        bool v = row < Ee;
        const float* p = e + row * 128 + q4 * 8;
#pragma unroll
        for (int kc = 0; kc < 4; ++kc) {
            float4 x = make_float4(0.f, 0.f, 0.f, 0.f);
            float4 y = make_float4(0.f, 0.f, 0.f, 0.f);
            if (v) {
                x = *reinterpret_cast<const float4*>(p + kc * 32);
                y = *reinterpret_cast<const float4*>(p + kc * 32 + 4);
            }
            afr[t][kc] = cvt8(x, y);
        }
    }

    // src/dst for this lane's 8 (t,r) edges: broadcast within each 16-lane quad
    int sreg[2][4], dreg[2][4];
#pragma unroll
    for (int t = 0; t < 2; ++t)
#pragma unroll
        for (int r = 0; r < 4; ++r) {
            long ge = e0 + (wave * 2 + t) * 16 + q4 * 4 + r;
            bool v = ge < Ee;
            sreg[t][r] = v ? src[ge] : 0;
            dreg[t][r] = v ? dst[ge] : 0;
        }

#pragma unroll 1
    for (int hg = 0; hg < 4; ++hg) {  // 2 heads per group (bounds VGPRs)
        // Phase A: pe accumulators for both heads, both t
        floatx4 acc[2][2];
        float bev[2];
#pragma unroll
        for (int hh = 0; hh < 2; ++hh) {
            int head = hg * 2 + hh;
            short8 bfr[4];
#pragma unroll
            for (int kc = 0; kc < 4; ++kc) bfr[kc] = wfrag(We, head * 16 + col, kc * 32 + q4 * 8);
            bev[hh] = be[head * 16 + col];
#pragma unroll
            for (int t = 0; t < 2; ++t) {
                floatx4 a = {0.f, 0.f, 0.f, 0.f};
#pragma unroll
                for (int kc = 0; kc < 4; ++kc)
                    a = __builtin_amdgcn_mfma_f32_16x16x32_bf16(afr[t][kc], bfr[kc], a, 0, 0, 0);
                acc[hh][t] = a;
            }
        }
        // Phase B: epilogue — batch independent gathers before consuming
#pragma unroll
        for (int t = 0; t < 2; ++t) {
#pragma unroll
            for (int r = 0; r < 4; ++r) {
                long ge = e0 + (wave * 2 + t) * 16 + q4 * 4 + r;
                bool valid = ge < Ee;
                int s32 = sreg[t][r], d32 = dreg[t][r];
                float kv[2], qv[2], vv[2];
#pragma unroll
                for (int hh = 0; hh < 2; ++hh) {
                    int hoff = (hg * 2 + hh) * 16 + col;
                    kv[hh] = K[(size_t)s32 * 128 + hoff];
                    qv[hh] = Q[(size_t)d32 * 128 + hoff];
                    vv[hh] = V[(size_t)s32 * 128 + hoff];
                }
#pragma unroll
                for (int hh = 0; hh < 2; ++hh) {
                    int head = hg * 2 + hh;
                    int hoff = head * 16 + col;
                    float pe = acc[hh][t][r] + bev[hh];
                    float score = kv[hh] * qv[hh] * 0.25f * pe;  // 1/sqrt(16)
                    if (valid) e_out[ge * 128 + hoff] = score;
                    // sum over 16 head dims: butterfly across the quad's 16 lanes
                    float sum = score;
                    sum += __shfl_xor(sum, 1, 16);
                    sum += __shfl_xor(sum, 2, 16);
                    sum += __shfl_xor(sum, 4, 16);
                    sum += __shfl_xor(sum, 8, 16);
                    float sval = __expf(fminf(fmaxf(sum, -5.0f), 5.0f));
                    if (valid) {
                        atomicAdd(&hacc[(size_t)d32 * 128 + hoff], vv[hh] * sval);
                        if (col == 0) atomicAdd(&z[(size_t)d32 * 8 + head], sval);
                    }
                }
            }
        }
    }
}

// ---------------- Finalize: h_out = acc / (z + 1e-6) ----------------
__global__ __launch_bounds__(256) void finalize(float* __restrict__ hacc, const float* __restrict__ z) {
    int i = blockIdx.x * 256 + threadIdx.x;
    int base = i * 4;  // 4 consecutive d within one head
    if (base < Nn * 128) {
        float4 a = *reinterpret_cast<float4*>(&hacc[base]);
        int node = base >> 7;
        int head = (base >> 4) & 7;
        float inv = 1.0f / (z[node * 8 + head] + 1e-6f);
        a.x *= inv; a.y *= inv; a.z *= inv; a.w *= inv;
        *reinterpret_cast<float4*>(&hacc[base]) = a;
    }
}

extern "C" void kernel_launch(void* const* d_in, const int* in_sizes, int n_in,
                              void* d_out, int out_size, void* d_ws, size_t ws_size,
                              hipStream_t stream) {
    const float* h  = (const float*)d_in[0];
    const float* e  = (const float*)d_in[1];
    const int*   src = (const int*)d_in[2];
    const int*   dst = (const int*)d_in[3];
    const float* Wq = (const float*)d_in[4];  const float* bq = (const float*)d_in[5];
    const float* Wk = (const float*)d_in[6];  const float* bk = (const float*)d_in[7];
    const float* Wv = (const float*)d_in[8];  const float* bv = (const float*)d_in[9];
    const float* We = (const float*)d_in[10]; const float* be = (const float*)d_in[11];

    float* out  = (float*)d_out;
    float* hout = out;                          // [N, H*D] = 6.4M floats
    float* eout = out + (size_t)Nn * 128;       // [E, H*D] = 80M floats

    float* ws = (float*)d_ws;                   // needs 78.4 MB
    float* Q = ws;
    float* K = ws + (size_t)Nn * 128;
    float* V = ws + 2 * (size_t)Nn * 128;
    float* z = ws + 3 * (size_t)Nn * 128;       // [N, H]

    hipMemsetAsync(hout, 0, (size_t)Nn * 128 * sizeof(float), stream);
    hipMemsetAsync(z, 0, (size_t)Nn * NH * sizeof(float), stream);

    node_qkv<<<dim3((Nn + 127) / 128, 3), 256, 0, stream>>>(h, Wq, bq, Wk, bk, Wv, bv, Q, K, V);
    edge_fused<<<(Ee + 127) / 128, 256, 0, stream>>>(e, src, dst, We, be, Q, K, V, eout, hout, z);
    finalize<<<(Nn * 128 / 4 + 255) / 256, 256, 0, stream>>>(hout, z);
}